// Round 3
// baseline (150.814 us; speedup 1.0000x reference)
//
#include <hip/hip_runtime.h>

// Problem constants (from reference)
static constexpr int      B_TOTAL  = 4194304;
static constexpr unsigned POS_MASK = 0xD2u; // classes 1,4,6,7 POSITIVE: bits 1,4,6,7
static constexpr int      BLOCKS   = 2048;
static constexpr int      THREADS  = 256;

__device__ __forceinline__ float fast_exp2(float x) {
#if __has_builtin(__builtin_amdgcn_exp2f)
    return __builtin_amdgcn_exp2f(x);
#else
    return exp2f(x);
#endif
}

__device__ __forceinline__ float fast_log2(float x) {
#if __has_builtin(__builtin_amdgcn_logf)
    return __builtin_amdgcn_logf(x);
#else
    return log2f(x);
#endif
}

// Weighted CE for one 8-class sample held in two float4s.
// Polarity of argmax computed WITHOUT the argmax index:
//   mp = max over positive classes {1,4,6,7}, mn = max over negative {0,2,3,5}
//   predicted polarity = (mp > mn). Cross-group exact ties (measure-zero on
//   random float data) may differ from first-occurrence argmax; effect on the
//   mean is ~1e-7, far below the 0.126 tolerance.
__device__ __forceinline__ float wce8(const float4 lo, const float4 hi,
                                      const int lbl, const unsigned lblPol) {
    constexpr float LOG2E = 1.4426950408889634f;
    constexpr float LN2   = 0.6931471805599453f;

    const float mp = fmaxf(fmaxf(lo.y, hi.x), fmaxf(hi.z, hi.w)); // x1,x4,x6,x7
    const float mn = fmaxf(fmaxf(lo.x, lo.z), fmaxf(lo.w, hi.y)); // x0,x2,x3,x5
    const float m  = fmaxf(mp, mn);

    const float c = -m * LOG2E;
    float s;
    s  = fast_exp2(fmaf(lo.x, LOG2E, c));
    s += fast_exp2(fmaf(lo.y, LOG2E, c));
    s += fast_exp2(fmaf(lo.z, LOG2E, c));
    s += fast_exp2(fmaf(lo.w, LOG2E, c));
    s += fast_exp2(fmaf(hi.x, LOG2E, c));
    s += fast_exp2(fmaf(hi.y, LOG2E, c));
    s += fast_exp2(fmaf(hi.z, LOG2E, c));
    s += fast_exp2(fmaf(hi.w, LOG2E, c));

    // x[lbl] via select chain (compile-time indices only — no scratch)
    float xl = lo.x;
    xl = (lbl == 1) ? lo.y : xl;
    xl = (lbl == 2) ? lo.z : xl;
    xl = (lbl == 3) ? lo.w : xl;
    xl = (lbl == 4) ? hi.x : xl;
    xl = (lbl == 5) ? hi.y : xl;
    xl = (lbl == 6) ? hi.z : xl;
    xl = (lbl == 7) ? hi.w : xl;

    const unsigned predPol = (mp > mn) ? 1u : 0u;
    const float w = (lblPol != predPol) ? 1.5f : 1.0f;

    // ce = m + ln2*log2(s) - xl
    return (fmaf(LN2, fast_log2(s), m) - xl) * w;
}

// Wave + block reduce; result valid on thread 0 only.
__device__ __forceinline__ float block_reduce(float acc, float* smem) {
    #pragma unroll
    for (int off = 32; off > 0; off >>= 1)
        acc += __shfl_down(acc, off);
    const int wave = threadIdx.x >> 6;
    if ((threadIdx.x & 63) == 0) smem[wave] = acc;
    __syncthreads();
    float t = 0.0f;
    if (threadIdx.x == 0) {
        #pragma unroll
        for (int w = 0; w < THREADS / 64; ++w) t += smem[w];
    }
    return t;
}

// Fused: streaming weighted-CE + per-block partial + last-block-done final
// reduce (deterministic: one block sums partials in fixed index order).
__global__ __launch_bounds__(THREADS) void pcce_fused(
    const float* __restrict__ a, const float* __restrict__ v,
    const int* __restrict__ y, float* __restrict__ out,
    float* __restrict__ partials, unsigned* __restrict__ counter, const int n)
{
    __shared__ float smem[THREADS / 64];
    __shared__ int   s_last;

    const float4* __restrict__ a4 = reinterpret_cast<const float4*>(a);
    const float4* __restrict__ v4 = reinterpret_cast<const float4*>(v);
    const int tid    = blockIdx.x * blockDim.x + threadIdx.x;
    const int stride = gridDim.x * blockDim.x;

    float acc = 0.0f;
    int i = tid;
    const int iters = n / stride; // exact 8 with default launch

    #pragma unroll 2
    for (int it = 0; it < iters; ++it) {
        const int lbl = y[i];
        const float4 alo = a4[2 * i], ahi = a4[2 * i + 1];
        const float4 vlo = v4[2 * i], vhi = v4[2 * i + 1];
        const unsigned lp = (POS_MASK >> lbl) & 1u;
        acc += wce8(alo, ahi, lbl, lp);
        acc += wce8(vlo, vhi, lbl, lp);
        i += stride;
    }
    for (; i < n; i += stride) { // tail (empty with default launch)
        const int lbl = y[i];
        const float4 alo = a4[2 * i], ahi = a4[2 * i + 1];
        const float4 vlo = v4[2 * i], vhi = v4[2 * i + 1];
        const unsigned lp = (POS_MASK >> lbl) & 1u;
        acc += wce8(alo, ahi, lbl, lp);
        acc += wce8(vlo, vhi, lbl, lp);
    }

    const float t = block_reduce(acc, smem);
    if (threadIdx.x == 0) {
        partials[blockIdx.x] = t;
        __threadfence();                       // release partials (device scope)
        const unsigned old = atomicAdd(counter, 1u);
        s_last = (old == (unsigned)(gridDim.x - 1));
    }
    __syncthreads();

    if (s_last) {
        __threadfence();                       // acquire all partials
        float r = 0.0f;
        for (int j = threadIdx.x; j < (int)gridDim.x; j += THREADS)
            r += partials[j];                  // fixed per-thread order
        __syncthreads();                       // smem reuse hazard
        const float total = block_reduce(r, smem);
        if (threadIdx.x == 0)
            out[0] = total * (1.0f / (float)B_TOTAL);
    }
}

// Fallback two-kernel path (only if ws is unexpectedly tiny).
__global__ __launch_bounds__(THREADS) void pcce_main(
    const float* __restrict__ a, const float* __restrict__ v,
    const int* __restrict__ y, float* __restrict__ partials, const int n)
{
    __shared__ float smem[THREADS / 64];
    const float4* __restrict__ a4 = reinterpret_cast<const float4*>(a);
    const float4* __restrict__ v4 = reinterpret_cast<const float4*>(v);
    const int tid    = blockIdx.x * blockDim.x + threadIdx.x;
    const int stride = gridDim.x * blockDim.x;

    float acc = 0.0f;
    for (int i = tid; i < n; i += stride) {
        const int lbl = y[i];
        const float4 alo = a4[2 * i], ahi = a4[2 * i + 1];
        const float4 vlo = v4[2 * i], vhi = v4[2 * i + 1];
        const unsigned lp = (POS_MASK >> lbl) & 1u;
        acc += wce8(alo, ahi, lbl, lp);
        acc += wce8(vlo, vhi, lbl, lp);
    }
    const float t = block_reduce(acc, smem);
    if (threadIdx.x == 0) partials[blockIdx.x] = t;
}

__global__ __launch_bounds__(256) void pcce_reduce(
    const float* __restrict__ partials, const int nb, float* __restrict__ out)
{
    __shared__ float smem[4];
    float acc = 0.0f;
    for (int i = threadIdx.x; i < nb; i += 256) acc += partials[i];
    #pragma unroll
    for (int off = 32; off > 0; off >>= 1)
        acc += __shfl_down(acc, off);
    if ((threadIdx.x & 63) == 0) smem[threadIdx.x >> 6] = acc;
    __syncthreads();
    if (threadIdx.x == 0)
        out[0] = (smem[0] + smem[1] + smem[2] + smem[3]) * (1.0f / (float)B_TOTAL);
}

extern "C" void kernel_launch(void* const* d_in, const int* in_sizes, int n_in,
                              void* d_out, int out_size, void* d_ws, size_t ws_size,
                              hipStream_t stream) {
    const float* a = (const float*)d_in[0];
    const float* v = (const float*)d_in[1];
    const int*   y = (const int*)d_in[2];
    float* out = (float*)d_out;
    const int n = in_sizes[2]; // B

    if (ws_size >= (size_t)(BLOCKS + 1) * sizeof(float)) {
        float*    partials = (float*)d_ws;
        unsigned* counter  = (unsigned*)((char*)d_ws + (size_t)BLOCKS * sizeof(float));
        // counter must be 0 every call (ws poisoned to 0xAA once, never restored)
        hipMemsetAsync(counter, 0, sizeof(unsigned), stream);
        pcce_fused<<<BLOCKS, THREADS, 0, stream>>>(a, v, y, out, partials, counter, n);
    } else {
        float* partials = (float*)d_ws; // even tiny ws fits 2048 floats? guard anyway
        pcce_main<<<BLOCKS, THREADS, 0, stream>>>(a, v, y, partials, n);
        pcce_reduce<<<1, 256, 0, stream>>>(partials, BLOCKS, out);
    }
}

// Round 4
// 78.673 us; speedup vs baseline: 1.9170x; 1.9170x over previous
//
#include <hip/hip_runtime.h>

// Problem constants (from reference)
static constexpr int      B_TOTAL  = 4194304;
static constexpr unsigned POS_MASK = 0xD2u; // classes 1,4,6,7 POSITIVE: bits 1,4,6,7
static constexpr int      BLOCKS   = 2048;  // 8 blocks/CU x 256 CU: whole grid resident
static constexpr int      THREADS  = 256;
static constexpr double   FXP_SCALE = 1048576.0; // 2^20 fixed-point for deterministic sum

__device__ __forceinline__ float fast_exp2(float x) {
#if __has_builtin(__builtin_amdgcn_exp2f)
    return __builtin_amdgcn_exp2f(x);
#else
    return exp2f(x);
#endif
}

__device__ __forceinline__ float fast_log2(float x) {
#if __has_builtin(__builtin_amdgcn_logf)
    return __builtin_amdgcn_logf(x);
#else
    return log2f(x);
#endif
}

// Weighted CE for one 8-class sample held in two float4s.
// Polarity of argmax computed WITHOUT the argmax index:
//   mp = max over positive classes {1,4,6,7}, mn = max over negative {0,2,3,5}
//   predicted polarity = (mp > mn). Cross-group exact ties (measure-zero on
//   random float data) may differ from first-occurrence argmax; effect on the
//   mean is ~1e-7, far below the 0.126 tolerance.
__device__ __forceinline__ float wce8(const float4 lo, const float4 hi,
                                      const int lbl, const unsigned lblPol) {
    constexpr float LOG2E = 1.4426950408889634f;
    constexpr float LN2   = 0.6931471805599453f;

    const float mp = fmaxf(fmaxf(lo.y, hi.x), fmaxf(hi.z, hi.w)); // x1,x4,x6,x7
    const float mn = fmaxf(fmaxf(lo.x, lo.z), fmaxf(lo.w, hi.y)); // x0,x2,x3,x5
    const float m  = fmaxf(mp, mn);

    const float c = -m * LOG2E;
    float s;
    s  = fast_exp2(fmaf(lo.x, LOG2E, c));
    s += fast_exp2(fmaf(lo.y, LOG2E, c));
    s += fast_exp2(fmaf(lo.z, LOG2E, c));
    s += fast_exp2(fmaf(lo.w, LOG2E, c));
    s += fast_exp2(fmaf(hi.x, LOG2E, c));
    s += fast_exp2(fmaf(hi.y, LOG2E, c));
    s += fast_exp2(fmaf(hi.z, LOG2E, c));
    s += fast_exp2(fmaf(hi.w, LOG2E, c));

    // x[lbl] via select chain (compile-time indices only — no scratch)
    float xl = lo.x;
    xl = (lbl == 1) ? lo.y : xl;
    xl = (lbl == 2) ? lo.z : xl;
    xl = (lbl == 3) ? lo.w : xl;
    xl = (lbl == 4) ? hi.x : xl;
    xl = (lbl == 5) ? hi.y : xl;
    xl = (lbl == 6) ? hi.z : xl;
    xl = (lbl == 7) ? hi.w : xl;

    const unsigned predPol = (mp > mn) ? 1u : 0u;
    const float w = (lblPol != predPol) ? 1.5f : 1.0f;

    // ce = m + ln2*log2(s) - xl
    return (fmaf(LN2, fast_log2(s), m) - xl) * w;
}

// Wave + block reduce; result valid on thread 0 only.
__device__ __forceinline__ float block_reduce(float acc, float* smem) {
    #pragma unroll
    for (int off = 32; off > 0; off >>= 1)
        acc += __shfl_down(acc, off);
    const int wave = threadIdx.x >> 6;
    if ((threadIdx.x & 63) == 0) smem[wave] = acc;
    __syncthreads();
    float t = 0.0f;
    if (threadIdx.x == 0) {
        #pragma unroll
        for (int w = 0; w < THREADS / 64; ++w) t += smem[w];
    }
    return t;
}

// Single kernel, NO device fences: deterministic int64 fixed-point atomic sum.
// Integer addition is associative -> bit-identical result for any block order.
// Ordering acc-add -> ticket-add via s_waitcnt vmcnt(0) (wait for completion
// at the device-coherent point; no L2 writeback, unlike __threadfence).
__global__ __launch_bounds__(THREADS) void pcce_one(
    const float* __restrict__ a, const float* __restrict__ v,
    const int* __restrict__ y, float* __restrict__ out,
    unsigned long long* __restrict__ acc_fxp, unsigned* __restrict__ ticket,
    const int n)
{
    __shared__ float smem[THREADS / 64];

    const float4* __restrict__ a4 = reinterpret_cast<const float4*>(a);
    const float4* __restrict__ v4 = reinterpret_cast<const float4*>(v);
    const int tid    = blockIdx.x * blockDim.x + threadIdx.x;
    const int stride = gridDim.x * blockDim.x;

    float acc = 0.0f;
    for (int i = tid; i < n; i += stride) {
        const int lbl = y[i];
        const float4 alo = a4[2 * i], ahi = a4[2 * i + 1];
        const float4 vlo = v4[2 * i], vhi = v4[2 * i + 1];
        const unsigned lp = (POS_MASK >> lbl) & 1u;
        acc += wce8(alo, ahi, lbl, lp);
        acc += wce8(vlo, vhi, lbl, lp);
    }

    const float t = block_reduce(acc, smem);
    if (threadIdx.x == 0) {
        // quantize partial (CE >= 0 so q >= 0); double keeps quantization at 2^-21
        const unsigned long long q =
            (unsigned long long)llrint((double)t * FXP_SCALE);
        atomicAdd(acc_fxp, q);
        // complete the acc atomic before the ticket atomic issues
        __asm__ volatile("s_waitcnt vmcnt(0)" ::: "memory");
        const unsigned old = atomicAdd(ticket, 1u);
        if (old == (unsigned)(gridDim.x - 1)) {
            // all acc adds completed (each was vmcnt-drained before its ticket);
            // atomic read at the coherent point sees the full sum
            const unsigned long long total = atomicAdd(acc_fxp, 0ULL);
            out[0] = (float)((double)total * (1.0 / FXP_SCALE) / (double)B_TOTAL);
        }
    }
}

// Fallback two-kernel path (only if ws is unexpectedly tiny).
__global__ __launch_bounds__(THREADS) void pcce_main(
    const float* __restrict__ a, const float* __restrict__ v,
    const int* __restrict__ y, float* __restrict__ partials, const int n)
{
    __shared__ float smem[THREADS / 64];
    const float4* __restrict__ a4 = reinterpret_cast<const float4*>(a);
    const float4* __restrict__ v4 = reinterpret_cast<const float4*>(v);
    const int tid    = blockIdx.x * blockDim.x + threadIdx.x;
    const int stride = gridDim.x * blockDim.x;

    float acc = 0.0f;
    for (int i = tid; i < n; i += stride) {
        const int lbl = y[i];
        const float4 alo = a4[2 * i], ahi = a4[2 * i + 1];
        const float4 vlo = v4[2 * i], vhi = v4[2 * i + 1];
        const unsigned lp = (POS_MASK >> lbl) & 1u;
        acc += wce8(alo, ahi, lbl, lp);
        acc += wce8(vlo, vhi, lbl, lp);
    }
    const float t = block_reduce(acc, smem);
    if (threadIdx.x == 0) partials[blockIdx.x] = t;
}

__global__ __launch_bounds__(256) void pcce_reduce(
    const float* __restrict__ partials, const int nb, float* __restrict__ out)
{
    __shared__ float smem[4];
    float acc = 0.0f;
    for (int i = threadIdx.x; i < nb; i += 256) acc += partials[i];
    #pragma unroll
    for (int off = 32; off > 0; off >>= 1)
        acc += __shfl_down(acc, off);
    if ((threadIdx.x & 63) == 0) smem[threadIdx.x >> 6] = acc;
    __syncthreads();
    if (threadIdx.x == 0)
        out[0] = (smem[0] + smem[1] + smem[2] + smem[3]) * (1.0f / (float)B_TOTAL);
}

extern "C" void kernel_launch(void* const* d_in, const int* in_sizes, int n_in,
                              void* d_out, int out_size, void* d_ws, size_t ws_size,
                              hipStream_t stream) {
    const float* a = (const float*)d_in[0];
    const float* v = (const float*)d_in[1];
    const int*   y = (const int*)d_in[2];
    float* out = (float*)d_out;
    const int n = in_sizes[2]; // B

    if (ws_size >= 16) {
        unsigned long long* acc_fxp = (unsigned long long*)d_ws;      // [0,8)
        unsigned*           ticket  = (unsigned*)((char*)d_ws + 8);   // [8,12)
        // acc + ticket must be zero every call (ws is poisoned once, not restored)
        hipMemsetAsync(d_ws, 0, 16, stream);
        pcce_one<<<BLOCKS, THREADS, 0, stream>>>(a, v, y, out, acc_fxp, ticket, n);
    } else {
        float* partials = (float*)d_ws;
        pcce_main<<<BLOCKS, THREADS, 0, stream>>>(a, v, y, partials, n);
        pcce_reduce<<<1, 256, 0, stream>>>(partials, BLOCKS, out);
    }
}

// Round 5
// 51.984 us; speedup vs baseline: 2.9012x; 1.5134x over previous
//
#include <hip/hip_runtime.h>

// Problem constants (from reference)
static constexpr int      B_TOTAL  = 4194304;
static constexpr unsigned POS_MASK = 0xD2u; // classes 1,4,6,7 POSITIVE: bits 1,4,6,7
static constexpr int      BLOCKS   = 2048;  // 8 blocks/CU x 256 CU: whole grid resident
static constexpr int      THREADS  = 256;

__device__ __forceinline__ float fast_exp2(float x) {
#if __has_builtin(__builtin_amdgcn_exp2f)
    return __builtin_amdgcn_exp2f(x);
#else
    return exp2f(x);
#endif
}

__device__ __forceinline__ float fast_log2(float x) {
#if __has_builtin(__builtin_amdgcn_logf)
    return __builtin_amdgcn_logf(x);
#else
    return log2f(x);
#endif
}

// Weighted CE for one 8-class sample held in two float4s.
// Polarity of argmax computed WITHOUT the argmax index:
//   mp = max over positive classes {1,4,6,7}, mn = max over negative {0,2,3,5}
//   predicted polarity = (mp > mn). Cross-group exact ties (measure-zero on
//   random float data) may differ from first-occurrence argmax; effect on the
//   mean is ~1e-7, far below the 0.126 tolerance.
__device__ __forceinline__ float wce8(const float4 lo, const float4 hi,
                                      const int lbl, const unsigned lblPol) {
    constexpr float LOG2E = 1.4426950408889634f;
    constexpr float LN2   = 0.6931471805599453f;

    const float mp = fmaxf(fmaxf(lo.y, hi.x), fmaxf(hi.z, hi.w)); // x1,x4,x6,x7
    const float mn = fmaxf(fmaxf(lo.x, lo.z), fmaxf(lo.w, hi.y)); // x0,x2,x3,x5
    const float m  = fmaxf(mp, mn);

    const float c = -m * LOG2E;
    float s;
    s  = fast_exp2(fmaf(lo.x, LOG2E, c));
    s += fast_exp2(fmaf(lo.y, LOG2E, c));
    s += fast_exp2(fmaf(lo.z, LOG2E, c));
    s += fast_exp2(fmaf(lo.w, LOG2E, c));
    s += fast_exp2(fmaf(hi.x, LOG2E, c));
    s += fast_exp2(fmaf(hi.y, LOG2E, c));
    s += fast_exp2(fmaf(hi.z, LOG2E, c));
    s += fast_exp2(fmaf(hi.w, LOG2E, c));

    // x[lbl] via select chain (compile-time indices only — no scratch)
    float xl = lo.x;
    xl = (lbl == 1) ? lo.y : xl;
    xl = (lbl == 2) ? lo.z : xl;
    xl = (lbl == 3) ? lo.w : xl;
    xl = (lbl == 4) ? hi.x : xl;
    xl = (lbl == 5) ? hi.y : xl;
    xl = (lbl == 6) ? hi.z : xl;
    xl = (lbl == 7) ? hi.w : xl;

    const unsigned predPol = (mp > mn) ? 1u : 0u;
    const float w = (lblPol != predPol) ? 1.5f : 1.0f;

    // ce = m + ln2*log2(s) - xl
    return (fmaf(LN2, fast_log2(s), m) - xl) * w;
}

// Wave + block reduce; result valid on thread 0 only.
__device__ __forceinline__ float block_reduce(float acc, float* smem) {
    #pragma unroll
    for (int off = 32; off > 0; off >>= 1)
        acc += __shfl_down(acc, off);
    const int wave = threadIdx.x >> 6;
    if ((threadIdx.x & 63) == 0) smem[wave] = acc;
    __syncthreads();
    float t = 0.0f;
    if (threadIdx.x == 0) {
        #pragma unroll
        for (int w = 0; w < THREADS / 64; ++w) t += smem[w];
    }
    return t;
}

// Streaming kernel, software-pipelined 1-ahead: issue sample k+1's 5 loads
// BEFORE computing sample k, so each wave keeps loads in flight under the
// ~160-cycle compute phase (MLP duty cycle ~100% instead of ~50%).
__global__ __launch_bounds__(THREADS) void pcce_main(
    const float* __restrict__ a, const float* __restrict__ v,
    const int* __restrict__ y, float* __restrict__ partials, const int n)
{
    __shared__ float smem[THREADS / 64];
    const float4* __restrict__ a4 = reinterpret_cast<const float4*>(a);
    const float4* __restrict__ v4 = reinterpret_cast<const float4*>(v);
    const int tid    = blockIdx.x * blockDim.x + threadIdx.x;
    const int stride = gridDim.x * blockDim.x;
    const int iters  = n / stride; // exact 8 with default launch

    float acc = 0.0f;
    if (iters > 0) {
        int i = tid;
        int    lbl = y[i];
        float4 alo = a4[2 * i], ahi = a4[2 * i + 1];
        float4 vlo = v4[2 * i], vhi = v4[2 * i + 1];

        for (int it = 1; it < iters; ++it) {
            const int j = i + stride;
            // prefetch next sample (5 loads issued before current compute)
            const int    lbln = y[j];
            const float4 alon = a4[2 * j], ahin = a4[2 * j + 1];
            const float4 vlon = v4[2 * j], vhin = v4[2 * j + 1];

            const unsigned lp = (POS_MASK >> lbl) & 1u;
            acc += wce8(alo, ahi, lbl, lp);
            acc += wce8(vlo, vhi, lbl, lp);

            i = j; lbl = lbln;
            alo = alon; ahi = ahin; vlo = vlon; vhi = vhin;
        }
        const unsigned lp = (POS_MASK >> lbl) & 1u;
        acc += wce8(alo, ahi, lbl, lp);
        acc += wce8(vlo, vhi, lbl, lp);
    }
    // tail (empty with default launch; kept for generality)
    for (int j = tid + iters * stride; j < n; j += stride) {
        const int lbl = y[j];
        const float4 alo = a4[2 * j], ahi = a4[2 * j + 1];
        const float4 vlo = v4[2 * j], vhi = v4[2 * j + 1];
        const unsigned lp = (POS_MASK >> lbl) & 1u;
        acc += wce8(alo, ahi, lbl, lp);
        acc += wce8(vlo, vhi, lbl, lp);
    }

    const float t = block_reduce(acc, smem);
    if (threadIdx.x == 0) partials[blockIdx.x] = t;
}

__global__ __launch_bounds__(256) void pcce_reduce(
    const float* __restrict__ partials, const int nb, float* __restrict__ out)
{
    __shared__ float smem[4];
    float acc = 0.0f;
    for (int i = threadIdx.x; i < nb; i += 256) acc += partials[i];
    #pragma unroll
    for (int off = 32; off > 0; off >>= 1)
        acc += __shfl_down(acc, off);
    if ((threadIdx.x & 63) == 0) smem[threadIdx.x >> 6] = acc;
    __syncthreads();
    if (threadIdx.x == 0)
        out[0] = (smem[0] + smem[1] + smem[2] + smem[3]) * (1.0f / (float)B_TOTAL);
}

extern "C" void kernel_launch(void* const* d_in, const int* in_sizes, int n_in,
                              void* d_out, int out_size, void* d_ws, size_t ws_size,
                              hipStream_t stream) {
    const float* a = (const float*)d_in[0];
    const float* v = (const float*)d_in[1];
    const int*   y = (const int*)d_in[2];
    float* out = (float*)d_out;
    const int n = in_sizes[2]; // B

    float* partials = (float*)d_ws; // 2048 floats = 8 KB, well within ws
    pcce_main<<<BLOCKS, THREADS, 0, stream>>>(a, v, y, partials, n);
    pcce_reduce<<<1, 256, 0, stream>>>(partials, BLOCKS, out);
}

// Round 6
// 50.592 us; speedup vs baseline: 2.9810x; 1.0275x over previous
//
#include <hip/hip_runtime.h>

// Problem constants (from reference)
static constexpr int      B_TOTAL  = 4194304;
static constexpr unsigned POS_MASK = 0xD2u; // classes 1,4,6,7 POSITIVE: bits 1,4,6,7
static constexpr int      BLOCKS   = 2048;  // 8 blocks/CU x 256 CU: whole grid resident
static constexpr int      THREADS  = 256;

__device__ __forceinline__ float fast_exp2(float x) {
#if __has_builtin(__builtin_amdgcn_exp2f)
    return __builtin_amdgcn_exp2f(x);
#else
    return exp2f(x);
#endif
}

__device__ __forceinline__ float fast_log2(float x) {
#if __has_builtin(__builtin_amdgcn_logf)
    return __builtin_amdgcn_logf(x);
#else
    return log2f(x);
#endif
}

// Weighted CE for one 8-class sample held in two float4s.
// Polarity of argmax computed WITHOUT the argmax index:
//   mp = max over positive classes {1,4,6,7}, mn = max over negative {0,2,3,5}
//   predicted polarity = (mp > mn). Cross-group exact ties (measure-zero on
//   random float data) may differ from first-occurrence argmax; effect on the
//   mean is ~1e-7, far below the 0.126 tolerance.
__device__ __forceinline__ float wce8(const float4 lo, const float4 hi,
                                      const int lbl, const unsigned lblPol) {
    constexpr float LOG2E = 1.4426950408889634f;
    constexpr float LN2   = 0.6931471805599453f;

    const float mp = fmaxf(fmaxf(lo.y, hi.x), fmaxf(hi.z, hi.w)); // x1,x4,x6,x7
    const float mn = fmaxf(fmaxf(lo.x, lo.z), fmaxf(lo.w, hi.y)); // x0,x2,x3,x5
    const float m  = fmaxf(mp, mn);

    const float c = -m * LOG2E;
    float s;
    s  = fast_exp2(fmaf(lo.x, LOG2E, c));
    s += fast_exp2(fmaf(lo.y, LOG2E, c));
    s += fast_exp2(fmaf(lo.z, LOG2E, c));
    s += fast_exp2(fmaf(lo.w, LOG2E, c));
    s += fast_exp2(fmaf(hi.x, LOG2E, c));
    s += fast_exp2(fmaf(hi.y, LOG2E, c));
    s += fast_exp2(fmaf(hi.z, LOG2E, c));
    s += fast_exp2(fmaf(hi.w, LOG2E, c));

    // x[lbl] via select chain (compile-time indices only — no scratch)
    float xl = lo.x;
    xl = (lbl == 1) ? lo.y : xl;
    xl = (lbl == 2) ? lo.z : xl;
    xl = (lbl == 3) ? lo.w : xl;
    xl = (lbl == 4) ? hi.x : xl;
    xl = (lbl == 5) ? hi.y : xl;
    xl = (lbl == 6) ? hi.z : xl;
    xl = (lbl == 7) ? hi.w : xl;

    const unsigned predPol = (mp > mn) ? 1u : 0u;
    const float w = (lblPol != predPol) ? 1.5f : 1.0f;

    // ce = m + ln2*log2(s) - xl
    return (fmaf(LN2, fast_log2(s), m) - xl) * w;
}

// Wave + block reduce; result valid on thread 0 only.
__device__ __forceinline__ float block_reduce(float acc, float* smem) {
    #pragma unroll
    for (int off = 32; off > 0; off >>= 1)
        acc += __shfl_down(acc, off);
    const int wave = threadIdx.x >> 6;
    if ((threadIdx.x & 63) == 0) smem[wave] = acc;
    __syncthreads();
    float t = 0.0f;
    if (threadIdx.x == 0) {
        #pragma unroll
        for (int w = 0; w < THREADS / 64; ++w) t += smem[w];
    }
    return t;
}

// Streaming kernel, software-pipelined 1-ahead with a HARD scheduling fence:
// sched_barrier(0) between "issue sample k+1's 5 loads" and "compute sample k"
// forbids the compiler from sinking the prefetch loads back to their uses
// (which it did in R5 — VGPR stayed 20). With the pin, the compiler's counted
// waitcnt insertion emits vmcnt(5)-class waits: sample k's data is drained
// while k+1's 5 loads stay in flight under the ~350-cycle compute phase.
__global__ __launch_bounds__(THREADS) void pcce_main(
    const float* __restrict__ a, const float* __restrict__ v,
    const int* __restrict__ y, float* __restrict__ partials, const int n)
{
    __shared__ float smem[THREADS / 64];
    const float4* __restrict__ a4 = reinterpret_cast<const float4*>(a);
    const float4* __restrict__ v4 = reinterpret_cast<const float4*>(v);
    const int tid    = blockIdx.x * blockDim.x + threadIdx.x;
    const int stride = gridDim.x * blockDim.x;
    const int iters  = n / stride; // exact 8 with default launch

    float acc = 0.0f;
    if (iters > 0) {
        int i = tid;
        int    lbl = y[i];
        float4 alo = a4[2 * i], ahi = a4[2 * i + 1];
        float4 vlo = v4[2 * i], vhi = v4[2 * i + 1];

        for (int it = 1; it < iters; ++it) {
            const int j = i + stride;
            // --- prefetch region: issue next sample's 5 loads ---
            const int    lbln = y[j];
            const float4 alon = a4[2 * j], ahin = a4[2 * j + 1];
            const float4 vlon = v4[2 * j], vhin = v4[2 * j + 1];
            // hard fence: nothing crosses — loads stay issued above,
            // compute stays below (waitcnt for alo..vhi lands here, counted)
            __builtin_amdgcn_sched_barrier(0);

            // --- compute region: sample k (prefetched last iteration) ---
            const unsigned lp = (POS_MASK >> lbl) & 1u;
            acc += wce8(alo, ahi, lbl, lp);
            acc += wce8(vlo, vhi, lbl, lp);

            i = j; lbl = lbln;
            alo = alon; ahi = ahin; vlo = vlon; vhi = vhin;
        }
        const unsigned lp = (POS_MASK >> lbl) & 1u;
        acc += wce8(alo, ahi, lbl, lp);
        acc += wce8(vlo, vhi, lbl, lp);
    }
    // tail (empty with default launch; kept for generality)
    for (int j = tid + iters * stride; j < n; j += stride) {
        const int lbl = y[j];
        const float4 alo = a4[2 * j], ahi = a4[2 * j + 1];
        const float4 vlo = v4[2 * j], vhi = v4[2 * j + 1];
        const unsigned lp = (POS_MASK >> lbl) & 1u;
        acc += wce8(alo, ahi, lbl, lp);
        acc += wce8(vlo, vhi, lbl, lp);
    }

    const float t = block_reduce(acc, smem);
    if (threadIdx.x == 0) partials[blockIdx.x] = t;
}

__global__ __launch_bounds__(256) void pcce_reduce(
    const float* __restrict__ partials, const int nb, float* __restrict__ out)
{
    __shared__ float smem[4];
    float acc = 0.0f;
    for (int i = threadIdx.x; i < nb; i += 256) acc += partials[i];
    #pragma unroll
    for (int off = 32; off > 0; off >>= 1)
        acc += __shfl_down(acc, off);
    if ((threadIdx.x & 63) == 0) smem[threadIdx.x >> 6] = acc;
    __syncthreads();
    if (threadIdx.x == 0)
        out[0] = (smem[0] + smem[1] + smem[2] + smem[3]) * (1.0f / (float)B_TOTAL);
}

extern "C" void kernel_launch(void* const* d_in, const int* in_sizes, int n_in,
                              void* d_out, int out_size, void* d_ws, size_t ws_size,
                              hipStream_t stream) {
    const float* a = (const float*)d_in[0];
    const float* v = (const float*)d_in[1];
    const int*   y = (const int*)d_in[2];
    float* out = (float*)d_out;
    const int n = in_sizes[2]; // B

    float* partials = (float*)d_ws; // 2048 floats = 8 KB, well within ws
    pcce_main<<<BLOCKS, THREADS, 0, stream>>>(a, v, y, partials, n);
    pcce_reduce<<<1, 256, 0, stream>>>(partials, BLOCKS, out);
}